// Round 10
// baseline (292.461 us; speedup 1.0000x reference)
//
#include <hip/hip_runtime.h>

// Problem constants
#define Gn 256
#define Nn 512
#define En 4096
#define Cn 16
#define ET (En + Nn)          // 4608 slots incl self-loops
#define QSLOT 2056            // per-quarter local CSR capacity (mean ~1160, +pad)

typedef _Float16 halfv8 __attribute__((ext_vector_type(8)));
typedef _Float16 halfv4 __attribute__((ext_vector_type(4)));
typedef _Float16 halfv2 __attribute__((ext_vector_type(2)));
typedef float    f32x4  __attribute__((ext_vector_type(4)));

__device__ __forceinline__ float pk_norm(unsigned p) {
    return (float)__builtin_bit_cast(_Float16, (unsigned short)(p & 0xffffu));
}

#if __has_builtin(__builtin_amdgcn_fdot2)
__device__ __forceinline__ float fdot2_(halfv2 a, halfv2 b, float c) {
    return __builtin_amdgcn_fdot2(a, b, c, false);
}
#else
__device__ __forceinline__ float fdot2_(halfv2 a, halfv2 b, float c) {
    return c + (float)a[0] * (float)b[0] + (float)a[1] * (float)b[1];
}
#endif
struct H2x4 { halfv2 p0, p1, p2, p3; };
__device__ __forceinline__ float dot8(halfv8 l, halfv8 h, float c) {
    H2x4 L = __builtin_bit_cast(H2x4, l);
    H2x4 H = __builtin_bit_cast(H2x4, h);
    c = fdot2_(L.p0, H.p0, c); c = fdot2_(L.p1, H.p1, c);
    c = fdot2_(L.p2, H.p2, c); c = fdot2_(L.p3, H.p3, c);
    return c;
}

// ---------------- K1: per-(graph,quarter) CSR + gather + MFMA conv; lw perm ---
// Blocks 0..1023: g = b>>2, hh = b&3 own targets [hh*128, hh*128+128).
// ~37 KB LDS, 256 thr -> 4 blocks/CU (16 waves/CU): barrier stalls of one
// block hide under the other three (R8's 1-block/CU chain lost ~30us to
// barrier drains; R9's split fixed that but paid more in launches/round-trips).
// h is written in MFMA D-frag order; blocks 1024..1151 write lwh in the SAME
// order (dot products are permutation-invariant) -> K2 streams both linearly.
__global__ __launch_bounds__(256, 4) void gcn_main(
    const float* __restrict__ x,      // [G,N,64] fp32
    const int*   __restrict__ ei,     // [G,2,E]
    const float* __restrict__ w,      // [64,64]
    const float* __restrict__ wbias,  // [64]
    const float* __restrict__ lw,     // [16, 32768] fp32
    _Float16* __restrict__ lwh,       // ws: [16][32768] f16, frag-permuted
    _Float16* __restrict__ hout)      // ws: [G][32768] f16, frag-permuted
{
    __shared__ int      degL[Nn];                // 2 KB
    __shared__ float    dinvL[Nn];               // 2 KB
    __shared__ int      cntl[128];               // 512 B: excl -> incl prefix
    __shared__ unsigned epkL[QSLOT + 8];         // 8.25 KB local CSR
    __shared__ unsigned short xhs[128 * 64];     // 16 KB aggregated, swizzled
    __shared__ unsigned short wts[64 * 64];      // 8 KB w rows, swizzled
    __shared__ int      wsum[2];

    const int b = blockIdx.x;
    const int tid = threadIdx.x, lane = tid & 63, wid = tid >> 6;

    if (b >= 1024) {
        // ---- lw fp32 -> f16, permuted to frag order ----
        // off(f16) = hh*8192 + tm*1024 + to*256 + q*64 + m*4 + e
        // n = hh*128+tm*16+m ; o = to*16+q*4+e
        int u = (b - 1024) * 256 + tid;          // 32768 threads
        #pragma unroll
        for (int r = 0; r < 4; ++r) {
            int idx = u * 4 + r;                 // halfv4 unit, 131072 total
            int c = idx >> 13, v4 = idx & 8191;
            int off = v4 * 4;
            int m  = (off >> 2) & 15, q  = (off >> 6) & 3;
            int to = (off >> 8) & 3,  tm = (off >> 10) & 7, hq = (off >> 13) & 3;
            int n = hq * 128 + tm * 16 + m, o = to * 16 + q * 4;
            float4 f = *(const float4*)(lw + (size_t)c * 32768 + n * 64 + o);
            halfv4 h; h[0]=(_Float16)f.x; h[1]=(_Float16)f.y;
                      h[2]=(_Float16)f.z; h[3]=(_Float16)f.w;
            *(halfv4*)(lwh + (size_t)c * 32768 + off) = h;
        }
        return;
    }

    const int g = b >> 2, hh = b & 3;
    const int*   es = ei + (size_t)g * 2 * En;
    const int*   ed = es + En;
    const float* xgf = x + (size_t)g * (Nn * 64);

    // ---- zero degrees + stage swizzled f16 W ----
    degL[tid] = 0; degL[tid + 256] = 0;
    #pragma unroll
    for (int it = 0; it < 2; ++it) {
        int idx = tid + it * 256;                // 512 jobs: o x b8
        int o = idx >> 3, b8 = idx & 7;
        float4 va = *(const float4*)(w + o * 64 + b8 * 8);
        float4 vb = *(const float4*)(w + o * 64 + b8 * 8 + 4);
        halfv8 hv; hv[0]=(_Float16)va.x; hv[1]=(_Float16)va.y;
                   hv[2]=(_Float16)va.z; hv[3]=(_Float16)va.w;
                   hv[4]=(_Float16)vb.x; hv[5]=(_Float16)vb.y;
                   hv[6]=(_Float16)vb.z; hv[7]=(_Float16)vb.w;
        *(halfv8*)((char*)wts + o * 128 + ((b8 ^ (o & 7)) * 16)) = hv;
    }
    __syncthreads();

    // ---- degrees (all nodes; needed for source dinv too) ----
    for (int e = tid; e < En; e += 256) atomicAdd(&degL[ed[e]], 1);
    __syncthreads();

    // ---- dinv (all) + exclusive scan of local quarter's slot counts ----
    dinvL[tid]       = rsqrtf((float)(degL[tid] + 1));
    dinvL[tid + 256] = rsqrtf((float)(degL[tid + 256] + 1));
    int c = 0;
    if (tid < 128) c = degL[hh * 128 + tid] + 1;   // slots incl self-loop
    int v = c;
    #pragma unroll
    for (int off = 1; off < 64; off <<= 1) {
        int u = __shfl_up(v, off, 64);
        if (lane >= off) v += u;
    }
    if (tid == 63) wsum[0] = v;                    // wave0 total
    __syncthreads();
    if (tid < 128) cntl[tid] = v - c + ((tid >= 64) ? wsum[0] : 0);
    __syncthreads();

    // ---- fill local CSR with packed (src<<16)|f16(norm), incl self-loops ----
    for (int e = tid; e < ET; e += 256) {
        int s, t;
        if (e < En) { s = es[e]; t = ed[e]; } else { s = t = e - En; }
        if ((t >> 7) == hh) {
            float nrm = dinvL[s] * dinvL[t];
            int slot = atomicAdd(&cntl[t & 127], 1);   // cntl becomes inclusive
            unsigned short nb = __builtin_bit_cast(unsigned short, (_Float16)nrm);
            epkL[slot] = ((unsigned)s << 16) | nb;
        }
    }
    __syncthreads();

    // ---- gather: quarter-wave per local target; x fp32 rows from L2 ----
    {
        const int qid = lane >> 4, fl = lane & 15;  // lane owns feats fl*4..+3
        for (int r = 0; r < 8; ++r) {
            int tl = r * 16 + wid * 4 + qid;        // local target 0..127
            int beg = (tl == 0) ? 0 : cntl[tl - 1];
            int end = cntl[tl];
            float a0 = 0.f, a1 = 0.f, a2 = 0.f, a3 = 0.f;
            unsigned pA0 = epkL[beg],     pA1 = epkL[beg + 1];
            unsigned pA2 = epkL[beg + 2], pA3 = epkL[beg + 3];
            int j = beg;
            for (; j + 4 <= end; j += 4) {
                unsigned pB0 = epkL[j + 4], pB1 = epkL[j + 5];
                unsigned pB2 = epkL[j + 6], pB3 = epkL[j + 7];
                int s0 = pA0 >> 16, s1 = pA1 >> 16, s2 = pA2 >> 16, s3 = pA3 >> 16;
                float n0 = pk_norm(pA0), n1 = pk_norm(pA1);
                float n2 = pk_norm(pA2), n3 = pk_norm(pA3);
                float4 x0 = *(const float4*)(xgf + s0 * 64 + fl * 4);
                float4 x1 = *(const float4*)(xgf + s1 * 64 + fl * 4);
                float4 x2 = *(const float4*)(xgf + s2 * 64 + fl * 4);
                float4 x3 = *(const float4*)(xgf + s3 * 64 + fl * 4);
                a0 += n0 * x0.x + n1 * x1.x + n2 * x2.x + n3 * x3.x;
                a1 += n0 * x0.y + n1 * x1.y + n2 * x2.y + n3 * x3.y;
                a2 += n0 * x0.z + n1 * x1.z + n2 * x2.z + n3 * x3.z;
                a3 += n0 * x0.w + n1 * x1.w + n2 * x2.w + n3 * x3.w;
                pA0 = pB0; pA1 = pB1; pA2 = pB2; pA3 = pB3;
            }
            for (; j < end; ++j) {                   // tail (<=3)
                int s = pA0 >> 16;
                float nm = pk_norm(pA0);
                float4 xv = *(const float4*)(xgf + s * 64 + fl * 4);
                a0 += nm * xv.x; a1 += nm * xv.y; a2 += nm * xv.z; a3 += nm * xv.w;
                pA0 = pA1; pA1 = pA2; pA2 = pA3;
            }
            halfv4 hv; hv[0]=(_Float16)a0; hv[1]=(_Float16)a1;
                       hv[2]=(_Float16)a2; hv[3]=(_Float16)a3;
            int dw = tl * 32 + (((fl >> 1) ^ (tl & 7)) * 4) + (fl & 1) * 2;
            *(halfv4*)((char*)xhs + dw * 4) = hv;
        }
    }
    __syncthreads();

    // ---- conv: D[o][n] tiles via MFMA; h stored frag-ordered (coalesced) ----
    {
        const int m = lane & 15, q = lane >> 4;
        #pragma unroll
        for (int j = 0; j < 8; ++j) {
            int idx = wid * 8 + j;                   // 32 jobs: 8 tm x 4 to
            int tm = idx >> 2, to = idx & 3;
            int n = tm * 16 + m;                     // local node 0..127
            int o = to * 16 + m;
            halfv8 X0 = *(const halfv8*)((const char*)xhs + n * 128 + ((q       ^ (n & 7)) * 16));
            halfv8 X1 = *(const halfv8*)((const char*)xhs + n * 128 + (((4 + q) ^ (n & 7)) * 16));
            halfv8 W0 = *(const halfv8*)((const char*)wts + o * 128 + ((q       ^ (o & 7)) * 16));
            halfv8 W1 = *(const halfv8*)((const char*)wts + o * 128 + (((4 + q) ^ (o & 7)) * 16));
            f32x4 acc = {0.f, 0.f, 0.f, 0.f};
            acc = __builtin_amdgcn_mfma_f32_16x16x32_f16(W0, X0, acc, 0, 0, 0);
            acc = __builtin_amdgcn_mfma_f32_16x16x32_f16(W1, X1, acc, 0, 0, 0);
            float4 bq = *(const float4*)&wbias[to * 16 + q * 4];
            halfv4 hv;
            hv[0] = (_Float16)fmaxf(acc[0] + bq.x, 0.0f);
            hv[1] = (_Float16)fmaxf(acc[1] + bq.y, 0.0f);
            hv[2] = (_Float16)fmaxf(acc[2] + bq.z, 0.0f);
            hv[3] = (_Float16)fmaxf(acc[3] + bq.w, 0.0f);
            // frag order: off = ((hh*8+tm)*4+to)*256 + lane*4
            size_t off = (size_t)g * 32768
                       + (size_t)((((hh * 8 + tm) * 4 + to) * 256) + lane * 4);
            *(halfv4*)(hout + off) = hv;             // 512B/wave, coalesced
        }
    }
}

// ---------------- K2: per-graph linear + log_softmax ----------------
// 256 blocks x 512 thr. Thread owns 64-elem permuted-k slice; dots vs all 16
// classes (lwh 1 MB/block, L2-resident per XCD). Block reduce -> softmax.
__global__ __launch_bounds__(512, 4) void gcn_out(
    const _Float16* __restrict__ h,    // ws: [G][32768] f16 (permuted)
    const _Float16* __restrict__ lwh,  // ws: [16][32768] f16 (same perm)
    const float* __restrict__ lbias,   // [16]
    float* __restrict__ out)           // [G,16]
{
    __shared__ float red[8][Cn];
    const int g = blockIdx.x, tid = threadIdx.x;
    const int lane = tid & 63, wid = tid >> 6;

    const halfv8* hg = (const halfv8*)(h + (size_t)g * 32768 + tid * 64);
    halfv8 hr0 = hg[0], hr1 = hg[1], hr2 = hg[2], hr3 = hg[3];
    halfv8 hr4 = hg[4], hr5 = hg[5], hr6 = hg[6], hr7 = hg[7];

    float p[Cn];
    #pragma unroll
    for (int c = 0; c < Cn; ++c) {
        const halfv8* lp = (const halfv8*)(lwh + (size_t)c * 32768 + tid * 64);
        halfv8 l0 = lp[0], l1 = lp[1], l2 = lp[2], l3 = lp[3];
        halfv8 l4 = lp[4], l5 = lp[5], l6 = lp[6], l7 = lp[7];
        float a = 0.f;
        a = dot8(l0, hr0, a); a = dot8(l1, hr1, a);
        a = dot8(l2, hr2, a); a = dot8(l3, hr3, a);
        a = dot8(l4, hr4, a); a = dot8(l5, hr5, a);
        a = dot8(l6, hr6, a); a = dot8(l7, hr7, a);
        p[c] = a;
    }
    #pragma unroll
    for (int c = 0; c < Cn; ++c) {
        float v = p[c];
        #pragma unroll
        for (int off = 32; off > 0; off >>= 1) v += __shfl_down(v, off, 64);
        if (lane == 0) red[wid][c] = v;
    }
    __syncthreads();
    if (wid == 0 && lane < Cn) {
        float v = lbias[lane];
        #pragma unroll
        for (int k = 0; k < 8; ++k) v += red[k][lane];
        float m = v;
        #pragma unroll
        for (int off = 8; off > 0; off >>= 1) m = fmaxf(m, __shfl_xor(m, off, 16));
        float ex = expf(v - m);
        float ssum = ex;
        #pragma unroll
        for (int off = 8; off > 0; off >>= 1) ssum += __shfl_xor(ssum, off, 16);
        out[g * Cn + lane] = v - m - logf(ssum);
    }
}

extern "C" void kernel_launch(void* const* d_in, const int* in_sizes, int n_in,
                              void* d_out, int out_size, void* d_ws, size_t ws_size,
                              hipStream_t stream) {
    const float* x  = (const float*)d_in[0];
    const int*   ei = (const int*)d_in[1];
    const float* w  = (const float*)d_in[2];
    const float* wb = (const float*)d_in[3];
    const float* lw = (const float*)d_in[4];
    const float* lb = (const float*)d_in[5];
    float* out = (float*)d_out;

    char* wsp = (char*)d_ws;
    _Float16* lwh  = (_Float16*)(wsp);               // 1,048,576 B
    _Float16* hbuf = (_Float16*)(wsp + 1048576);     // 16,777,216 B

    hipLaunchKernelGGL(gcn_main, dim3(1152), dim3(256), 0, stream,
                       x, ei, w, wb, lw, lwh, hbuf);
    hipLaunchKernelGGL(gcn_out, dim3(Gn), dim3(512), 0, stream,
                       hbuf, lwh, lb, out);
}

// Round 11
// 137.978 us; speedup vs baseline: 2.1196x; 2.1196x over previous
//
#include <hip/hip_runtime.h>

// Problem constants
#define Gn 256
#define Nn 512
#define En 4096
#define Cn 16
#define ET (En + Nn)        // 4608 CSR slots incl self-loops
#define EPAD 4616           // per-graph epk stride in ws (u32 units)

typedef _Float16 halfv8 __attribute__((ext_vector_type(8)));
typedef _Float16 halfv4 __attribute__((ext_vector_type(4)));
typedef float    f32x4  __attribute__((ext_vector_type(4)));

__device__ __forceinline__ float pk_norm(unsigned p) {
    return (float)__builtin_bit_cast(_Float16, (unsigned short)(p & 0xffffu));
}

// ---------------- K1: per-graph CSR build -> ws (proven R9, ~5us) ----------------
__global__ __launch_bounds__(256) void build_csr(const int* __restrict__ ei,
                                                 unsigned* __restrict__ epkG,
                                                 int* __restrict__ cntG) {
    __shared__ int      degL[Nn];
    __shared__ float    dinvL[Nn];
    __shared__ int      cntE[Nn];
    __shared__ unsigned epkL[ET];
    __shared__ int      wsum[4];
    const int g = blockIdx.x, tid = threadIdx.x;
    const int lane = tid & 63, wid = tid >> 6;
    const int* es = ei + (size_t)g * 2 * En;
    const int* ed = es + En;

    degL[tid] = 0; degL[tid + 256] = 0;
    __syncthreads();
    for (int e = tid; e < En; e += 256) atomicAdd(&degL[ed[e]], 1);
    __syncthreads();

    const int t2 = tid * 2;
    int cA = degL[t2] + 1, cB = degL[t2 + 1] + 1;   // slots incl self-loop
    dinvL[t2]     = rsqrtf((float)cA);
    dinvL[t2 + 1] = rsqrtf((float)cB);
    int p = cA + cB, v = p;
    #pragma unroll
    for (int off = 1; off < 64; off <<= 1) {
        int u = __shfl_up(v, off, 64);
        if (lane >= off) v += u;
    }
    if (lane == 63) wsum[wid] = v;
    __syncthreads();
    if (tid == 0) { int a = 0; for (int i = 0; i < 4; ++i) { int t = wsum[i]; wsum[i] = a; a += t; } }
    __syncthreads();
    int pe = v - p + wsum[wid];                     // exclusive prefix at node t2
    cntE[t2] = pe;
    cntE[t2 + 1] = pe + cA;
    __syncthreads();

    for (int e = tid; e < ET; e += 256) {
        int s, t;
        if (e < En) { s = es[e]; t = ed[e]; } else { s = t = e - En; }
        float nrm = dinvL[s] * dinvL[t];
        int slot = atomicAdd(&cntE[t], 1);          // cntE becomes inclusive
        unsigned short nb = __builtin_bit_cast(unsigned short, (_Float16)nrm);
        epkL[slot] = ((unsigned)s << 16) | nb;
    }
    __syncthreads();

    for (int i = tid; i < ET; i += 256) epkG[(size_t)g * EPAD + i] = epkL[i];
    cntG[(size_t)g * Nn + t2]     = cntE[t2];
    cntG[(size_t)g * Nn + t2 + 1] = cntE[t2 + 1];
}

// ---------------- K2: gather ONLY (isolated for profiling) ----------------
// grid (2, Gn) x 512 thr, ~20 KB LDS -> 4 blocks/CU. Quarter-wave per target;
// x fp32 rows straight from L2 (no cvt_x pass); result written as f16 natural
// [g][n][f] with 128B-contiguous segments per quarter-wave.
__global__ __launch_bounds__(512) void gather_k(
    const float*    __restrict__ x,     // [G,N,64] fp32
    const unsigned* __restrict__ epkG,  // ws: [G][EPAD]
    const int*      __restrict__ cntG,  // ws: [G][N] inclusive
    _Float16* __restrict__ xhg)         // ws: [G][512][64] f16 natural
{
    __shared__ unsigned epkL[ET + 8];   // 18.5 KB (worst-case half)
    __shared__ int cntl[260];
    const int hh = blockIdx.x, g = blockIdx.y;
    const int tid = threadIdx.x, lane = tid & 63, wid = tid >> 6;
    const int tbase = hh * 256;

    const int slotlo = (hh == 0) ? 0 : cntG[(size_t)g * Nn + tbase - 1];
    const int slothi = cntG[(size_t)g * Nn + tbase + 255];
    const int total  = slothi - slotlo;

    if (tid < 257)
        cntl[tid] = (tid == 0) ? slotlo : cntG[(size_t)g * Nn + tbase + tid - 1];
    for (int i = tid; i < total; i += 512)
        epkL[i] = epkG[(size_t)g * EPAD + slotlo + i];
    __syncthreads();

    const float* xgf = x + (size_t)g * (Nn * 64);
    const int qid = lane >> 4, fl = lane & 15;      // lane owns feats fl*4..+3
    for (int r = 0; r < 8; ++r) {
        int tl = r * 32 + wid * 4 + qid;            // local target 0..255
        int beg = cntl[tl] - slotlo;
        int end = cntl[tl + 1] - slotlo;
        float a0 = 0.f, a1 = 0.f, a2 = 0.f, a3 = 0.f;
        unsigned pA0 = epkL[beg],     pA1 = epkL[beg + 1];
        unsigned pA2 = epkL[beg + 2], pA3 = epkL[beg + 3];
        int j = beg;
        for (; j + 4 <= end; j += 4) {
            unsigned pB0 = epkL[j + 4], pB1 = epkL[j + 5];
            unsigned pB2 = epkL[j + 6], pB3 = epkL[j + 7];
            int s0 = pA0 >> 16, s1 = pA1 >> 16, s2 = pA2 >> 16, s3 = pA3 >> 16;
            float n0 = pk_norm(pA0), n1 = pk_norm(pA1);
            float n2 = pk_norm(pA2), n3 = pk_norm(pA3);
            float4 x0 = *(const float4*)(xgf + s0 * 64 + fl * 4);
            float4 x1 = *(const float4*)(xgf + s1 * 64 + fl * 4);
            float4 x2 = *(const float4*)(xgf + s2 * 64 + fl * 4);
            float4 x3 = *(const float4*)(xgf + s3 * 64 + fl * 4);
            a0 += n0 * x0.x + n1 * x1.x + n2 * x2.x + n3 * x3.x;
            a1 += n0 * x0.y + n1 * x1.y + n2 * x2.y + n3 * x3.y;
            a2 += n0 * x0.z + n1 * x1.z + n2 * x2.z + n3 * x3.z;
            a3 += n0 * x0.w + n1 * x1.w + n2 * x2.w + n3 * x3.w;
            pA0 = pB0; pA1 = pB1; pA2 = pB2; pA3 = pB3;
        }
        for (; j < end; ++j) {                       // tail (<=3)
            int s = pA0 >> 16;
            float nm = pk_norm(pA0);
            float4 xv = *(const float4*)(xgf + s * 64 + fl * 4);
            a0 += nm * xv.x; a1 += nm * xv.y; a2 += nm * xv.z; a3 += nm * xv.w;
            pA0 = pA1; pA1 = pA2; pA2 = pA3;
        }
        halfv4 hv; hv[0]=(_Float16)a0; hv[1]=(_Float16)a1;
                   hv[2]=(_Float16)a2; hv[3]=(_Float16)a3;
        // natural layout: quarter-wave writes one 128B-contiguous row chunk
        *(halfv4*)(xhg + (size_t)g * 32768 + (tbase + tl) * 64 + fl * 4) = hv;
    }
}

// ---------------- K3: MFMA conv (+ lw permute in hh==2 blocks) ----------------
// grid (3, Gn) x 256 thr. hh<2: stage 256 xh rows (coalesced) into swizzled
// LDS, 2xMFMA per 16x16 o-tile, write h frag-ordered. hh==2: lw fp32->f16 in
// the SAME frag order (dot is perm-invariant) -> K4 streams both linearly.
__global__ __launch_bounds__(256) void conv_k(
    const _Float16* __restrict__ xhg,   // ws: [G][512][64] f16
    const float*    __restrict__ w,     // [64,64]
    const float*    __restrict__ wbias, // [64]
    const float*    __restrict__ lw,    // [16][32768] fp32
    _Float16* __restrict__ lwh,         // ws: [16][32768] f16 frag-permuted
    _Float16* __restrict__ hout)        // ws: [G][32768] f16 frag-permuted
{
    __shared__ unsigned short xhs[256 * 64];   // 32 KB swizzled
    __shared__ unsigned short wts[64 * 64];    // 8 KB swizzled
    const int hh = blockIdx.x, g = blockIdx.y;
    const int tid = threadIdx.x, lane = tid & 63, wid = tid >> 6;

    if (hh == 2) {
        // lw permute: off(f16) = jobidx*256 + q*64 + m*4 + e;
        // jobidx = (n>>4)*4 + to ; n = (jobidx>>2)*16+m ; o = to*16+q*4+e
        int u0 = (g * 256 + tid) * 2;            // 2 halfv4 units per thread
        #pragma unroll
        for (int r = 0; r < 2; ++r) {
            int idx = u0 + r;                    // 0..131071
            int c = idx >> 13, v4 = idx & 8191;
            int jobidx = v4 >> 6, q = (v4 >> 4) & 3, m = v4 & 15;
            int n = (jobidx >> 2) * 16 + m;
            int o = (jobidx & 3) * 16 + q * 4;
            float4 f = *(const float4*)(lw + (size_t)c * 32768 + n * 64 + o);
            halfv4 h; h[0]=(_Float16)f.x; h[1]=(_Float16)f.y;
                      h[2]=(_Float16)f.z; h[3]=(_Float16)f.w;
            *(halfv4*)(lwh + (size_t)c * 32768 + (size_t)v4 * 4) = h;
        }
        return;
    }

    // ---- stage W swizzled ----
    #pragma unroll
    for (int it = 0; it < 2; ++it) {
        int idx = tid + it * 256;                // 512 jobs: o x b8
        int o = idx >> 3, b8 = idx & 7;
        float4 va = *(const float4*)(w + o * 64 + b8 * 8);
        float4 vb = *(const float4*)(w + o * 64 + b8 * 8 + 4);
        halfv8 hv; hv[0]=(_Float16)va.x; hv[1]=(_Float16)va.y;
                   hv[2]=(_Float16)va.z; hv[3]=(_Float16)va.w;
                   hv[4]=(_Float16)vb.x; hv[5]=(_Float16)vb.y;
                   hv[6]=(_Float16)vb.z; hv[7]=(_Float16)vb.w;
        *(halfv8*)((char*)wts + o * 128 + ((b8 ^ (o & 7)) * 16)) = hv;
    }
    // ---- stage this half's 256 xh rows, coalesced read -> swizzled LDS ----
    {
        const _Float16* src = xhg + (size_t)g * 32768 + hh * 256 * 64;
        #pragma unroll
        for (int it = 0; it < 8; ++it) {
            int u = tid + it * 256;              // 2048 halfv8 units, lane-major b8
            int b8 = u & 7, n = u >> 3;
            halfv8 v = *(const halfv8*)(src + n * 64 + b8 * 8);
            *(halfv8*)((char*)xhs + n * 128 + ((b8 ^ (n & 7)) * 16)) = v;
        }
    }
    __syncthreads();

    // ---- conv: D[o][n] tiles; h stored frag-ordered (coalesced) ----
    const int m = lane & 15, q = lane >> 4;
    #pragma unroll
    for (int j = 0; j < 16; ++j) {
        int idx = wid * 16 + j;                  // 64 jobs: 16 tm x 4 to
        int tm = idx >> 2, to = idx & 3;
        int n = tm * 16 + m;                     // local node 0..255
        int o = to * 16 + m;
        halfv8 X0 = *(const halfv8*)((const char*)xhs + n * 128 + ((q       ^ (n & 7)) * 16));
        halfv8 X1 = *(const halfv8*)((const char*)xhs + n * 128 + (((4 + q) ^ (n & 7)) * 16));
        halfv8 W0 = *(const halfv8*)((const char*)wts + o * 128 + ((q       ^ (o & 7)) * 16));
        halfv8 W1 = *(const halfv8*)((const char*)wts + o * 128 + (((4 + q) ^ (o & 7)) * 16));
        f32x4 acc = {0.f, 0.f, 0.f, 0.f};
        acc = __builtin_amdgcn_mfma_f32_16x16x32_f16(W0, X0, acc, 0, 0, 0);
        acc = __builtin_amdgcn_mfma_f32_16x16x32_f16(W1, X1, acc, 0, 0, 0);
        float4 bq = *(const float4*)&wbias[to * 16 + q * 4];
        halfv4 hv;
        hv[0] = (_Float16)fmaxf(acc[0] + bq.x, 0.0f);
        hv[1] = (_Float16)fmaxf(acc[1] + bq.y, 0.0f);
        hv[2] = (_Float16)fmaxf(acc[2] + bq.z, 0.0f);
        hv[3] = (_Float16)fmaxf(acc[3] + bq.w, 0.0f);
        // frag order: jobidx_global = (hh*16+tm)*4+to
        size_t off = (size_t)g * 32768
                   + (size_t)((((hh * 16 + tm) * 4 + to) * 256) + lane * 4);
        *(halfv4*)(hout + off) = hv;             // 512B/wave, coalesced
    }
}

// ---------------- K4: logits partials via MFMA over permuted k (proven R9) ----
__global__ __launch_bounds__(256) void linear_mfma(
    const _Float16* __restrict__ h,    // ws: [256][32768] f16 (permuted)
    const _Float16* __restrict__ lwh,  // ws: [16][32768] f16 (same perm)
    float* __restrict__ part)          // ws: [256][32][16]
{
    __shared__ float red[4][64][4];
    const int cx = blockIdx.x, gy = blockIdx.y;
    const int tid = threadIdx.x, lane = tid & 63, wid = tid >> 6;
    const int ml = lane & 15, q = lane >> 4;
    const size_t kbase = (size_t)cx * 1024 + wid * 256;
    const _Float16* ha = h   + (size_t)(gy * 16 + ml) * 32768 + kbase + q * 8;
    const _Float16* lb = lwh + (size_t)ml * 32768 + kbase + q * 8;

    f32x4 acc = {0.f, 0.f, 0.f, 0.f};
    #pragma unroll
    for (int ks = 0; ks < 8; ++ks) {
        halfv8 a = *(const halfv8*)(ha + ks * 32);
        halfv8 b = *(const halfv8*)(lb + ks * 32);
        acc = __builtin_amdgcn_mfma_f32_16x16x32_f16(a, b, acc, 0, 0, 0);
    }
    #pragma unroll
    for (int r = 0; r < 4; ++r) red[wid][lane][r] = acc[r];
    __syncthreads();
    {
        int m = tid >> 4, cc = tid & 15;      // D: row=(lane>>4)*4+reg, col=lane&15
        int sl = (m >> 2) * 16 + cc, rg = m & 3;
        float v = red[0][sl][rg] + red[1][sl][rg] + red[2][sl][rg] + red[3][sl][rg];
        part[((size_t)(gy * 16 + m) * 32 + cx) * Cn + cc] = v;
    }
}

// ---------------- K5: reduce 32 slices + bias + log_softmax ----------------
__global__ __launch_bounds__(64) void gcn_softmax(
    const float* __restrict__ part, const float* __restrict__ lbias,
    float* __restrict__ out)
{
    const int g = blockIdx.x, lane = threadIdx.x;
    if (lane < Cn) {
        float v = lbias[lane];
        #pragma unroll
        for (int s = 0; s < 32; ++s) v += part[((size_t)g * 32 + s) * Cn + lane];
        float m = v;
        #pragma unroll
        for (int off = 8; off > 0; off >>= 1) m = fmaxf(m, __shfl_xor(m, off, 16));
        float ex = expf(v - m);
        float ssum = ex;
        #pragma unroll
        for (int off = 8; off > 0; off >>= 1) ssum += __shfl_xor(ssum, off, 16);
        out[g * Cn + lane] = v - m - logf(ssum);
    }
}

extern "C" void kernel_launch(void* const* d_in, const int* in_sizes, int n_in,
                              void* d_out, int out_size, void* d_ws, size_t ws_size,
                              hipStream_t stream) {
    const float* x  = (const float*)d_in[0];
    const int*   ei = (const int*)d_in[1];
    const float* w  = (const float*)d_in[2];
    const float* wb = (const float*)d_in[3];
    const float* lw = (const float*)d_in[4];
    const float* lb = (const float*)d_in[5];
    float* out = (float*)d_out;

    char* wsp = (char*)d_ws;
    unsigned* epkG = (unsigned*)(wsp);                   //  4,726,784 B
    int*      cntG = (int*)     (wsp + 4726784);         //    524,288 B
    _Float16* xhg  = (_Float16*)(wsp + 5251072);         // 16,777,216 B
    _Float16* lwh  = (_Float16*)(wsp + 22028288);        //  1,048,576 B
    _Float16* hbuf = (_Float16*)(wsp + 23076864);        // 16,777,216 B
    float*    part = (float*)   (wsp + 39854080);        //    524,288 B

    hipLaunchKernelGGL(build_csr,   dim3(Gn),      dim3(256), 0, stream, ei, epkG, cntG);
    hipLaunchKernelGGL(gather_k,    dim3(2, Gn),   dim3(512), 0, stream, x, epkG, cntG, xhg);
    hipLaunchKernelGGL(conv_k,      dim3(3, Gn),   dim3(256), 0, stream,
                       xhg, w, wb, lw, lwh, hbuf);
    hipLaunchKernelGGL(linear_mfma, dim3(32, 16),  dim3(256), 0, stream, hbuf, lwh, part);
    hipLaunchKernelGGL(gcn_softmax, dim3(Gn),      dim3(64),  0, stream, part, lb, out);
}